// Round 9
// baseline (138.639 us; speedup 1.0000x reference)
//
#include <hip/hip_runtime.h>
#include <hip/hip_bf16.h>

#define DIM    286
#define DIMP   288
#define NBATCH 256
#define NB_    24
#define NA_    48
#define ZC     32        // z per tile
#define NTILES 1728      // 55296/32
#define NCHUNK 256       // k_main grid.x; 192 blocks x 7 tiles + 64 x 6
#define S_CONST 16.911534525287763f
#define INV_S   0.05913123959890826f
#define ACT_CST 1.5927f  // normalize2mom const for tanh
#define TWO_LOG2E 2.8853900817779268f   // 2*log2(e): expf(-2a) == exp2(-TWO_LOG2E*a)

typedef short bf16x8 __attribute__((ext_vector_type(8)));
typedef float f32x4  __attribute__((ext_vector_type(4)));

// ws layout (bytes) -- DT intermediate eliminated (D converted in-LDS inside k_main)
#define WS_FBF  0u                            // Fbf: 256*288*2 = 147456
#define WS_PART 147456u                       // part: 256*256*288*2 = 37748736

typedef const __attribute__((address_space(1))) char GA;
typedef __attribute__((address_space(3))) char LA;
__device__ __forceinline__ void gload_lds16(const void* g, void* l) {
    __builtin_amdgcn_global_load_lds((GA*)g, (LA*)l, 16, 0, 0);
}

// ---------- tiny prep: F -> bf16 [256][288] scaled by 1/s (288 blocks x 256 thr)
__global__ void k_prepF(const float* __restrict__ F, __hip_bfloat16* __restrict__ Fbf) {
    int o = blockIdx.x * 256 + threadIdx.x;   // 288*256 == 73728 exactly
    int row = o / DIMP, col = o % DIMP;
    float v = (col < DIM) ? F[row * DIM + col] * INV_S : 0.f;
    Fbf[o] = __float2bfloat16(v);
}

// ---------- fused main (R8 + convert/GEMM overlap): 512 thr, 8 waves x M=32,
// grid 256 (1 block/CU).  Ds/Dt DOUBLE-buffered: the region at iter k runs
// {GEMM1(k) + act(k) + GEMM2(k)} INTERLEAVED with convert(k+1) -> Ds/Dt[(k+1)&1],
// no barrier between them.  Traw dbuf + STAGE(k+2) at region top (full-region DMA
// hiding).  Gs = 1 KB/wave slot reused across the two h-phases (act h0 -> GEMM2a
// -> act h1 -> GEMM2b; WAR on the slot ordered by compiler lgkmcnt).
// REGISTER LAW (r0..r7): 512-thr block -> 256-reg cap; acc(144) forbids fa cache;
// A streams from L2-resident Fbf (unroll 3).
__launch_bounds__(512, 2)
__global__ void k_main(const __hip_bfloat16* __restrict__ Fbf,
                       const float* __restrict__ D,
                       const float* __restrict__ qw,
                       __hip_bfloat16* __restrict__ part) {
    __shared__ __align__(16) float Traw[2][9216];  // raw f32 tile dbuf: 73728 B
    __shared__ __align__(16) char DsB[2][18432];   // bf16 [ks][z][i32], hash ((z&7)<<4)
    __shared__ __align__(16) char DtB[2][18432];   // bf16 [i][z],      hash ((i&7)<<4)
    __shared__ __align__(16) char GsB[8192];       // per-wave 1KB G,   hash (q<<4)
    __shared__ float qs[24];
    // total LDS = 73728+36864+36864+8192+96 = 155744 B (<160 KiB)

    int t = threadIdx.x;
    int wave = t >> 6, lane = t & 63, ln = lane & 15, q = lane >> 4;
    int cA = (ln * 64 + q * 16) ^ ((ln & 7) << 4);
    // Gs 1KB slot addressing (rows folded &15; same bank hash as R8's row>>2 = q)
    int gA = (wave << 10) + ((ln * 64 + q * 16) ^ ((ln >> 2) << 4));

    if (t < 24) qs[t] = qw[t] * S_CONST;

    int rowbase = wave * 32;
    // A-frags stream from L2-resident Fbf (tile-invariant; NOT register-cached)
    const __hip_bfloat16* fp0 = Fbf + (size_t)(rowbase + ln) * DIMP + q * 8;
    const __hip_bfloat16* fp1 = fp0 + 16 * DIMP;

    f32x4 acc[2][18];
    #pragma unroll
    for (int h = 0; h < 2; ++h)
        #pragma unroll
        for (int n = 0; n < 18; ++n) acc[h][n] = (f32x4){0.f, 0.f, 0.f, 0.f};

    int bx = blockIdx.x;
    int tstart = (bx < 192) ? bx * 7 : bx * 6 + 192;   // 192*7 + 64*6 = 1728
    int ntile = (bx < 192) ? 7 : 6;

    // seed for the strength-reduced d -> (z, i2) walk (one div/mod total)
    int zseed = t / 144, iseed = t % 144;

    #define STAGE(TI, BUF) do {                                                    \
        const char* _s = (const char*)(D + (size_t)(tstart + (TI)) * 9152);        \
        char* _d = (char*)Traw[BUF];                                               \
        _Pragma("unroll")                                                          \
        for (int _j = 0; _j < 5; ++_j) {                                           \
            int _c = wave + _j * 8;                                                \
            if (_c < 35 || (_c == 35 && lane < 48))                                \
                gload_lds16(_s + _c * 1024 + lane * 16, _d + _c * 1024);           \
        }                                                                          \
    } while (0)

    // strength-reduced Ds convert: Traw[buf] -> DsB[buf2]
    #define CONV_DS(TBUF, DBUF) do {                                               \
        const float* _T = Traw[TBUF];                                              \
        char* _Ds = DsB[DBUF];                                                     \
        int zz = zseed, ii = iseed;                                                \
        _Pragma("unroll")                                                          \
        for (int m = 0; m < 9; ++m) {                                              \
            int i = ii * 2;                                                        \
            __hip_bfloat162 o2;                                                    \
            if (i < DIM) {                                                         \
                float2 v = *(const float2*)(&_T[zz * DIM + i]);                    \
                o2.x = __float2bfloat16(v.x); o2.y = __float2bfloat16(v.y);        \
            } else {                                                               \
                o2.x = __float2bfloat16(0.f); o2.y = o2.x;                         \
            }                                                                      \
            int off = (((i >> 5) * 2048) + zz * 64 + (i & 31) * 2) ^ ((zz & 7) << 4); \
            *(__hip_bfloat162*)(_Ds + off) = o2;                                   \
            zz += 3; ii += 80;                                                     \
            if (ii >= 144) { ii -= 144; ++zz; }                                    \
        }                                                                          \
    } while (0)

    // pure-transpose Dt convert: Traw[buf] -> DtB[buf2]
    #define CONV_DT(TBUF, DBUF) do {                                               \
        const float* _T = Traw[TBUF];                                              \
        char* _Dt = DtB[DBUF];                                                     \
        _Pragma("unroll")                                                          \
        for (int s5 = 0; s5 < 3; ++s5) {                                           \
            int idx = t + s5 * 512;                                                \
            if (idx < 1152) {                                                      \
                int i = idx >> 2, zc = idx & 3;                                    \
                __hip_bfloat16 o8[8];                                              \
                _Pragma("unroll")                                                  \
                for (int j = 0; j < 8; ++j)                                        \
                    o8[j] = __float2bfloat16(_T[(zc * 8 + j) * DIM + i]);          \
                int off = (i * 64 + zc * 16) ^ ((i & 7) << 4);                     \
                *(bf16x8*)(_Dt + off) = *(const bf16x8*)o8;                        \
            }                                                                      \
        }                                                                          \
    } while (0)

    // prologue: stage+convert tile 0; stage tile 1
    STAGE(0, 0);
    asm volatile("s_waitcnt vmcnt(0) lgkmcnt(0)" ::: "memory");  // DMA0 + qs store
    __builtin_amdgcn_s_barrier();
    STAGE(1, 1);
    CONV_DS(0, 0);
    CONV_DT(0, 0);
    asm volatile("s_waitcnt lgkmcnt(0)" ::: "memory");
    __builtin_amdgcn_s_barrier();

    #pragma unroll 1
    for (int k = 0; k < ntile; ++k) {
        int cur = k & 1, nxt = cur ^ 1;
        bool more = (k + 1 < ntile);
        if (more) {
            asm volatile("s_waitcnt vmcnt(0)" ::: "memory");   // DMA(k+1) landed
            __builtin_amdgcn_s_barrier();
            if (k + 2 < ntile) STAGE(k + 2, cur);              // (k+2)&1 == cur
        }
        const char* dsR = DsB[cur];
        const char* dtR = DtB[cur];

        // per-lane quadrature scale: qv(z) = qs[(z/48)%24], z = z0t + zh*16 + ln
        int z0t = (tstart + k) * 32;
        float qv0 = qs[((z0t + ln) / 48) % 24];
        float qv1 = qs[((z0t + 16 + ln) / 48) % 24];

        // ---- GEMM1: G[32 x 32] per wave, K=288 (A streamed, unroll 3)
        f32x4 g00 = (f32x4){0.f,0.f,0.f,0.f}, g01 = (f32x4){0.f,0.f,0.f,0.f};
        f32x4 g10 = (f32x4){0.f,0.f,0.f,0.f}, g11 = (f32x4){0.f,0.f,0.f,0.f};
        #pragma unroll 3
        for (int ks = 0; ks < 9; ++ks) {
            bf16x8 a0 = *(const bf16x8*)(fp0 + ks * 32);
            bf16x8 a1 = *(const bf16x8*)(fp1 + ks * 32);
            bf16x8 b0 = *(const bf16x8*)(dsR + ks * 2048 + cA);
            bf16x8 b1 = *(const bf16x8*)(dsR + ks * 2048 + 1024 + cA);
            g00 = __builtin_amdgcn_mfma_f32_16x16x32_bf16(a0, b0, g00, 0, 0, 0);
            g01 = __builtin_amdgcn_mfma_f32_16x16x32_bf16(a0, b1, g01, 0, 0, 0);
            g10 = __builtin_amdgcn_mfma_f32_16x16x32_bf16(a1, b0, g10, 0, 0, 0);
            g11 = __builtin_amdgcn_mfma_f32_16x16x32_bf16(a1, b1, g11, 0, 0, 0);
        }

        // ---- overlapped: convert Ds(k+1) while GEMM1 results settle
        if (more) CONV_DS(nxt, nxt);

        // ---- act h=0 -> Gs slot -> GEMM2a (acc[0])
        #pragma unroll
        for (int zh = 0; zh < 2; ++zh) {
            f32x4 g = (zh == 0) ? g00 : g01;
            float qv = (zh == 0) ? qv0 : qv1;
            #pragma unroll
            for (int r = 0; r < 4; ++r) {
                float x = g[r];
                float a = fabsf(x);
                float e = __builtin_amdgcn_exp2f(-TWO_LOG2E * a);
                float v = ACT_CST - 2.f * ACT_CST * e * __builtin_amdgcn_rcpf(1.f + e);
                v = copysignf(v, x) * qv;
                int goff = (wave << 10)
                         + (((q * 4 + r) * 64 + (zh * 16 + ln) * 2) ^ (q << 4));
                *(__hip_bfloat16*)(GsB + goff) = __float2bfloat16(v);
            }
        }
        {
            bf16x8 a20 = *(const bf16x8*)(GsB + gA);
            #pragma unroll
            for (int nf = 0; nf < 18; ++nf) {
                bf16x8 b2 = *(const bf16x8*)(dtR + nf * 1024 + cA);
                acc[0][nf] = __builtin_amdgcn_mfma_f32_16x16x32_bf16(a20, b2, acc[0][nf], 0, 0, 0);
            }
        }

        // ---- overlapped: convert Dt(k+1)
        if (more) CONV_DT(nxt, nxt);

        // ---- act h=1 -> same Gs slot (WAR vs a20 read: compiler lgkmcnt) -> GEMM2b
        #pragma unroll
        for (int zh = 0; zh < 2; ++zh) {
            f32x4 g = (zh == 0) ? g10 : g11;
            float qv = (zh == 0) ? qv0 : qv1;
            #pragma unroll
            for (int r = 0; r < 4; ++r) {
                float x = g[r];
                float a = fabsf(x);
                float e = __builtin_amdgcn_exp2f(-TWO_LOG2E * a);
                float v = ACT_CST - 2.f * ACT_CST * e * __builtin_amdgcn_rcpf(1.f + e);
                v = copysignf(v, x) * qv;
                int goff = (wave << 10)
                         + (((q * 4 + r) * 64 + (zh * 16 + ln) * 2) ^ (q << 4));
                *(__hip_bfloat16*)(GsB + goff) = __float2bfloat16(v);
            }
        }
        {
            bf16x8 a21 = *(const bf16x8*)(GsB + gA);
            #pragma unroll
            for (int nf = 0; nf < 18; ++nf) {
                bf16x8 b2 = *(const bf16x8*)(dtR + nf * 1024 + cA);
                acc[1][nf] = __builtin_amdgcn_mfma_f32_16x16x32_bf16(a21, b2, acc[1][nf], 0, 0, 0);
            }
        }

        if (more) {
            asm volatile("s_waitcnt lgkmcnt(0)" ::: "memory");  // convert writes done
            __builtin_amdgcn_s_barrier();                       // all waves done w/ cur
        }
    }
    #undef STAGE
    #undef CONV_DS
    #undef CONV_DT

    // epilogue: permuted coalesced layout, 18 b128 stores/thread.
    // elem ((h*9+m)*64 + lane)*8 + j  <=>  acc[h][2m + (j>>2)][j&3]
    __hip_bfloat16* pw = part + (size_t)bx * (NBATCH * DIMP) + (size_t)rowbase * DIMP;
    #pragma unroll
    for (int h = 0; h < 2; ++h) {
        #pragma unroll
        for (int m = 0; m < 9; ++m) {
            __hip_bfloat16 o8[8];
            #pragma unroll
            for (int j = 0; j < 8; ++j)
                o8[j] = __float2bfloat16(acc[h][2 * m + (j >> 2)][j & 3]);
            *(bf16x8*)(pw + (size_t)((h * 9 + m) * 64 + lane) * 8) = *(const bf16x8*)o8;
        }
    }
}

// ---------- reduce permuted bf16 partials over 256 z-chunks: 576 blocks x 16 slots
__global__ void k_reduce(const __hip_bfloat16* __restrict__ part, float* __restrict__ out) {
    __shared__ float red[3][16][8];
    int t = threadIdx.x, wave = t >> 6, lane = t & 63;
    int j = lane & 15;                 // slot within block
    int zg = wave * 4 + (lane >> 4);   // 0..15 zc-group
    int s = blockIdx.x * 16 + j;       // 576*16 = 9216 b128 slots per chunk
    const __hip_bfloat16* p = part + (size_t)s * 8;
    float sum[8];
    #pragma unroll
    for (int kk = 0; kk < 8; ++kk) sum[kk] = 0.f;
    #pragma unroll 4
    for (int ii = 0; ii < 16; ++ii) {
        bf16x8 v = *(const bf16x8*)(p + (size_t)(zg * 16 + ii) * (NBATCH * DIMP));
        #pragma unroll
        for (int kk = 0; kk < 8; ++kk) {
            __hip_bfloat16 h; *(short*)&h = v[kk];
            sum[kk] += __bfloat162float(h);
        }
    }
    #pragma unroll
    for (int kk = 0; kk < 8; ++kk) {
        sum[kk] += __shfl_down(sum[kk], 16);
        sum[kk] += __shfl_down(sum[kk], 32);
    }
    if (wave > 0 && lane < 16) {
        #pragma unroll
        for (int kk = 0; kk < 8; ++kk) red[wave - 1][lane][kk] = sum[kk];
    }
    __syncthreads();
    if (wave == 0 && lane < 16) {
        #pragma unroll
        for (int w = 0; w < 3; ++w)
            #pragma unroll
            for (int kk = 0; kk < 8; ++kk) sum[kk] += red[w][lane][kk];
        int wr = s / 1152, si = s % 1152;
        int lane_m = si % 64, m9 = si / 64;
        int h = m9 / 9, m = m9 % 9, q = lane_m >> 4, ln = lane_m & 15;
        int rowb = wr * 32 + h * 16 + q * 4;
        #pragma unroll
        for (int j8 = 0; j8 < 8; ++j8) {
            int nf = 2 * m + (j8 >> 2), r = j8 & 3;
            int i = nf * 16 + ln;
            if (i < DIM) out[(rowb + r) * DIM + i] = sum[j8];
        }
    }
}

extern "C" void kernel_launch(void* const* d_in, const int* in_sizes, int n_in,
                              void* d_out, int out_size, void* d_ws, size_t ws_size,
                              hipStream_t stream) {
    const float* F  = (const float*)d_in[0];
    const float* D  = (const float*)d_in[1];
    const float* qw = (const float*)d_in[2];
    char* ws = (char*)d_ws;
    __hip_bfloat16* Fbf = (__hip_bfloat16*)(ws + WS_FBF);
    __hip_bfloat16* part = (__hip_bfloat16*)(ws + WS_PART);

    k_prepF<<<288, 256, 0, stream>>>(F, Fbf);
    k_main<<<NCHUNK, 512, 0, stream>>>(Fbf, D, qw, part);
    k_reduce<<<576, 256, 0, stream>>>(part, (float*)d_out);
}